// Round 8
// baseline (1837.219 us; speedup 1.0000x reference)
//
#include <hip/hip_runtime.h>
#include <hip/hip_bf16.h>
#include <stdint.h>

#define VOCAB 50257
#define HID 512
#define LABELS 64
#define KSPLIT 4
#define KLEN (HID / KSPLIT)      // 128
#define CHUNK 32
#define NCHUNK (KLEN / CHUNK)    // 4

typedef __attribute__((address_space(1))) const void global_cvoid;
typedef __attribute__((address_space(3))) void lds_void;

// ---------------------------------------------------------------------------
// K0: C[l] = b2[l] + sum_h b1[h] * w2[l][h]   (the v-independent bias term)
// ---------------------------------------------------------------------------
__global__ void bias_combine(const float* __restrict__ b1,
                             const float* __restrict__ w2,
                             const float* __restrict__ b2,
                             float* __restrict__ C)
{
    int l = threadIdx.x;   // 64 threads
    float s = b2[l];
    for (int h = 0; h < HID; h += 4) {
        float4 wv = *(const float4*)&w2[l * HID + h];
        float4 bv = *(const float4*)&b1[h];
        s += wv.x * bv.x + wv.y * bv.y + wv.z * bv.z + wv.w * bv.w;
    }
    C[l] = s;
}

// ---------------------------------------------------------------------------
// K1 (fast path): P[s][v][l] = sum_{h in split s} w1[h,v]*w2[l,h]
// 64 cols x 64 labels per block, K=128 in 4 chunks of 32, DOUBLE-BUFFERED:
// chunk c+1's A-stage (global_load_lds, wave-uniform dest + lane*4) and
// B-loads (regs) issue BEFORE chunk c's compute; one barrier per chunk.
// Fully unrolled so buf indices are compile-time (disjoint LDS ranges).
// LDS stride 64 floats: all accesses broadcast/2-way -> conflict-free.
// ---------------------------------------------------------------------------
__global__ __launch_bounds__(256) void build_partial(
    const float* __restrict__ w1,   // [HID][VOCAB]
    const float* __restrict__ w2,   // [LABELS][HID]
    float* __restrict__ P)          // [KSPLIT][VOCAB][LABELS]
{
    __shared__ float ldsA[2][CHUNK * 64];   // [hh][col]
    __shared__ float ldsB[2][CHUNK * 64];   // [hh][label]

    const int t     = threadIdx.x;
    const int lane  = t & 63;
    const int w     = t >> 6;                 // wave 0..3
    const int v0    = blockIdx.x * 64;
    const int hbase = blockIdx.y * KLEN;
    float* Pout = P + (size_t)blockIdx.y * VOCAB * LABELS;
    const int tx = t & 15;                    // cols tx*4..tx*4+3
    const int ty = t >> 4;                    // labels ty*4..ty*4+3
    const bool full = (v0 + 64 <= VOCAB);

    float acc[4][4] = {};

    // stage A chunk c into ldsA[buf]: rows hbase+c*32 .. +31, cols v0..v0+63
    auto stageA = [&](int buf, int c) {
        const int h0 = hbase + c * CHUNK;
        if (full) {
#pragma unroll
            for (int i = 0; i < 8; ++i) {
                const int row = 4 * i + w;                    // uniform per wave
                const float* g = &w1[(size_t)(h0 + row) * VOCAB + v0 + lane];
                __builtin_amdgcn_global_load_lds(
                    (global_cvoid*)g,
                    (lds_void*)&ldsA[buf][row * 64],          // uniform base
                    4, 0, 0);
            }
        } else {
#pragma unroll
            for (int i = 0; i < 8; ++i) {
                const int row = 4 * i + w;
                const int v = v0 + lane;
                ldsA[buf][row * 64 + lane] =
                    (v < VOCAB) ? w1[(size_t)(h0 + row) * VOCAB + v] : 0.f;
            }
        }
    };
    // load B chunk c (w2^T slice [32][64]) into 2 float4 regs per thread
    auto loadB = [&](int c, float4* r) {
        const int h0 = hbase + c * CHUNK;
        const int l  = t & 63;
        const int hq = t >> 6;                                // 0..3
#pragma unroll
        for (int i = 0; i < 2; ++i)
            r[i] = *(const float4*)&w2[l * HID + h0 + (hq + 4 * i) * 4];
    };
    auto writeB = [&](int buf, const float4* r) {
        const int l  = t & 63;
        const int hq = t >> 6;
#pragma unroll
        for (int i = 0; i < 2; ++i) {
            const int hr = (hq + 4 * i) * 4;
            ldsB[buf][(hr + 0) * 64 + l] = r[i].x;
            ldsB[buf][(hr + 1) * 64 + l] = r[i].y;
            ldsB[buf][(hr + 2) * 64 + l] = r[i].z;
            ldsB[buf][(hr + 3) * 64 + l] = r[i].w;
        }
    };

    // ---- prologue: chunk 0 into buf 0
    {
        float4 b0[2];
        stageA(0, 0);
        loadB(0, b0);
        writeB(0, b0);
    }
    __syncthreads();   // drains glds (vmcnt) + ds_write (lgkm)

#pragma unroll
    for (int c = 0; c < NCHUNK; ++c) {
        const int buf = c & 1;                 // compile-time after unroll
        float4 nreg[2];
        if (c + 1 < NCHUNK) {                  // prefetch next chunk
            stageA(buf ^ 1, c + 1);
            loadB(c + 1, nreg);
        }
        // compute on current buffer (overlaps with in-flight prefetch)
#pragma unroll
        for (int hh = 0; hh < CHUNK; ++hh) {
            float4 a = *(const float4*)&ldsA[buf][hh * 64 + tx * 4];
            float4 b = *(const float4*)&ldsB[buf][hh * 64 + ty * 4];
            acc[0][0] += a.x * b.x; acc[0][1] += a.x * b.y; acc[0][2] += a.x * b.z; acc[0][3] += a.x * b.w;
            acc[1][0] += a.y * b.x; acc[1][1] += a.y * b.y; acc[1][2] += a.y * b.z; acc[1][3] += a.y * b.w;
            acc[2][0] += a.z * b.x; acc[2][1] += a.z * b.y; acc[2][2] += a.z * b.z; acc[2][3] += a.z * b.w;
            acc[3][0] += a.w * b.x; acc[3][1] += a.w * b.y; acc[3][2] += a.w * b.z; acc[3][3] += a.w * b.w;
        }
        if (c + 1 < NCHUNK) {
            writeB(buf ^ 1, nreg);             // other buffer: no race with readers of buf
            __syncthreads();                   // glds landed + B writes visible
        }
    }

#pragma unroll
    for (int i = 0; i < 4; ++i) {
        int v = v0 + tx * 4 + i;
        if (v < VOCAB) {
            *(float4*)&Pout[(size_t)v * LABELS + ty * 4] =
                make_float4(acc[i][0], acc[i][1], acc[i][2], acc[i][3]);
        }
    }
}

// ---------------------------------------------------------------------------
// K1 fallback (small ws): folded-b1 single-buffer version (R7 kernel).
// ---------------------------------------------------------------------------
__global__ __launch_bounds__(256) void build_partial_folded(
    const float* __restrict__ w1,
    const float* __restrict__ b1,
    const float* __restrict__ w2,
    float* __restrict__ P,
    int klen)
{
    __shared__ float lds_a[32 * 68];
    __shared__ float lds_b[32 * 68];

    const int t     = threadIdx.x;
    const int v0    = blockIdx.x * 64;
    const int hbase = blockIdx.y * klen;
    float* Pout = P + (size_t)blockIdx.y * VOCAB * LABELS;
    const int tx = t & 15;
    const int ty = t >> 4;
    const bool full = (v0 + 64 <= VOCAB);

    float acc[4][4] = {};

    for (int h0 = hbase; h0 < hbase + klen; h0 += 32) {
#pragma unroll
        for (int i = 0; i < 8; ++i) {
            int e   = t + 256 * i;
            int row = e >> 6;
            int col = e & 63;
            int v   = v0 + col;
            float a = (full || v < VOCAB) ? w1[(size_t)(h0 + row) * VOCAB + v] : 0.f;
            lds_a[row * 68 + col] = a + b1[h0 + row];
        }
#pragma unroll
        for (int i = 0; i < 2; ++i) {
            int e   = t + 256 * i;
            int hh4 = e >> 6;
            int l   = e & 63;
            float4 bv = *(const float4*)&w2[l * HID + h0 + hh4 * 4];
            lds_b[(hh4 * 4 + 0) * 68 + l] = bv.x;
            lds_b[(hh4 * 4 + 1) * 68 + l] = bv.y;
            lds_b[(hh4 * 4 + 2) * 68 + l] = bv.z;
            lds_b[(hh4 * 4 + 3) * 68 + l] = bv.w;
        }
        __syncthreads();
#pragma unroll
        for (int hh = 0; hh < 32; ++hh) {
            float4 a = *(const float4*)&lds_a[hh * 68 + tx * 4];
            float4 b = *(const float4*)&lds_b[hh * 68 + ty * 4];
            acc[0][0] += a.x * b.x; acc[0][1] += a.x * b.y; acc[0][2] += a.x * b.z; acc[0][3] += a.x * b.w;
            acc[1][0] += a.y * b.x; acc[1][1] += a.y * b.y; acc[1][2] += a.y * b.z; acc[1][3] += a.y * b.w;
            acc[2][0] += a.z * b.x; acc[2][1] += a.z * b.y; acc[2][2] += a.z * b.z; acc[2][3] += a.z * b.w;
            acc[3][0] += a.w * b.x; acc[3][1] += a.w * b.y; acc[3][2] += a.w * b.z; acc[3][3] += a.w * b.w;
        }
        __syncthreads();
    }

#pragma unroll
    for (int i = 0; i < 4; ++i) {
        int v = v0 + tx * 4 + i;
        if (v < VOCAB) {
            *(float4*)&Pout[(size_t)v * LABELS + ty * 4] =
                make_float4(acc[i][0], acc[i][1], acc[i][2], acc[i][3]);
        }
    }
}

// ---------------------------------------------------------------------------
// K2: out[tok][l] = sum_s P[s][idx[tok]][l] + bias[l]
// ---------------------------------------------------------------------------
__global__ __launch_bounds__(256) void gather_out(
    const int* __restrict__ idx,
    const float* __restrict__ P,
    const float* __restrict__ bias,
    float* __restrict__ out,
    int ntok, int ksplit)
{
    int g   = blockIdx.x * 256 + threadIdx.x;
    int tok = g >> 4;
    int j   = g & 15;
    if (tok >= ntok) return;
    int v = idx[tok];
    float4 s = ((const float4*)bias)[j];
    const float4* p = (const float4*)P + (size_t)v * 16 + j;
    for (int k = 0; k < ksplit; ++k) {
        float4 m = p[(size_t)k * VOCAB * 16];
        s.x += m.x; s.y += m.y; s.z += m.z; s.w += m.w;
    }
    ((float4*)out)[(size_t)tok * 16 + j] = s;
}

// ---------------------------------------------------------------------------
// Fallback (ws too small for any table): direct per-token dot.
// ---------------------------------------------------------------------------
__global__ __launch_bounds__(256) void direct_kernel(
    const int* __restrict__ idx,
    const float* __restrict__ w1,
    const float* __restrict__ b1,
    const float* __restrict__ w2,
    const float* __restrict__ b2,
    float* __restrict__ out,
    int ntok)
{
    int g   = blockIdx.x * 256 + threadIdx.x;
    int tok = g >> 6;
    int l   = g & 63;
    if (tok >= ntok) return;
    int v = idx[tok];
    float acc = b2[l];
    for (int h = 0; h < HID; ++h)
        acc += (w1[(size_t)h * VOCAB + v] + b1[h]) * w2[l * HID + h];
    out[(size_t)tok * 64 + l] = acc;
}

extern "C" void kernel_launch(void* const* d_in, const int* in_sizes, int n_in,
                              void* d_out, int out_size, void* d_ws, size_t ws_size,
                              hipStream_t stream) {
    const int*   idx = (const int*)d_in[0];
    const float* w1  = (const float*)d_in[1];
    const float* b1  = (const float*)d_in[2];
    const float* w2  = (const float*)d_in[3];
    const float* b2  = (const float*)d_in[4];
    float* out = (float*)d_out;
    const int ntok = in_sizes[0];   // 8*4096 = 32768

    const size_t table_bytes = (size_t)VOCAB * LABELS * sizeof(float);  // ~12.9 MB
    const int nblk2 = (ntok * 16 + 255) / 256;                          // 2048

    if (ws_size >= (size_t)KSPLIT * table_bytes + 1024) {
        // fast path: double-buffered build + separate bias vector C in ws tail
        float* P = (float*)d_ws;
        float* C = (float*)((char*)d_ws + (size_t)KSPLIT * table_bytes);
        bias_combine<<<1, 64, 0, stream>>>(b1, w2, b2, C);
        dim3 grid1((VOCAB + 63) / 64, KSPLIT);   // 786 x 4
        build_partial<<<grid1, 256, 0, stream>>>(w1, w2, P);
        gather_out<<<nblk2, 256, 0, stream>>>(idx, P, C, out, ntok, KSPLIT);
    } else {
        int ksplit = 0;
        if      (ws_size >= 4 * table_bytes) ksplit = 4;
        else if (ws_size >= 2 * table_bytes) ksplit = 2;
        else if (ws_size >= 1 * table_bytes) ksplit = 1;
        if (ksplit > 0) {
            float* P = (float*)d_ws;
            dim3 grid1((VOCAB + 63) / 64, ksplit);
            build_partial_folded<<<grid1, 256, 0, stream>>>(w1, b1, w2, P, HID / ksplit);
            gather_out<<<nblk2, 256, 0, stream>>>(idx, P, b2, out, ntok, ksplit);
        } else {
            int nblk = (ntok * 64 + 255) / 256;
            direct_kernel<<<nblk, 256, 0, stream>>>(idx, w1, b1, w2, b2, out, ntok);
        }
    }
}

// Round 9
// 123.981 us; speedup vs baseline: 14.8186x; 14.8186x over previous
//
#include <hip/hip_runtime.h>
#include <hip/hip_bf16.h>

#define VOCAB 50257
#define HID 512
#define LABELS 64

// ---------------------------------------------------------------------------
// K1: partial tables P[s][v][l] = sum_{h in split s} (w1[h,v]+b1[h])*w2[l,h]
// 128-thread block, tile 128 vocab-cols x 64 labels, K chunked by 32 via LDS.
// Thread tile 8x8 = dual 4-col groups {tx*4, 64+tx*4} x dual 4-label groups
// {ty*4, 32+ty*4}: every ds_read_b128 is stride-4-dword across 16 lanes
// (2-way, free) or broadcast. 4 b128 per 64 FMAs halves the LDS-issue time
// that bound R7 (measured: 2 b128/16 FMA -> LDS 63us vs VALU 21us).
// Pads: A pitch 132 (16B-aligned rows), B pitch 68.
// ---------------------------------------------------------------------------
__global__ __launch_bounds__(128) void build_partial(
    const float* __restrict__ w1,   // [HID][VOCAB]
    const float* __restrict__ b1,   // [HID]
    const float* __restrict__ w2,   // [LABELS][HID]
    float* __restrict__ P,          // [ksplit][VOCAB][LABELS]
    int klen)
{
    __shared__ float lds_a[32 * 132];  // [hh][col 0..127], b1 folded in
    __shared__ float lds_b[32 * 68];   // [hh][label 0..63]

    const int t     = threadIdx.x;      // 0..127
    const int v0    = blockIdx.x * 128;
    const int hbase = blockIdx.y * klen;
    float* Pout = P + (size_t)blockIdx.y * VOCAB * LABELS;
    const int tx = t & 15;              // col groups: tx*4 and 64+tx*4
    const int ty = t >> 4;              // label groups: ty*4 and 32+ty*4
    const bool full = (v0 + 128 <= VOCAB);

    float acc[8][8];
#pragma unroll
    for (int i = 0; i < 8; ++i)
#pragma unroll
        for (int j = 0; j < 8; ++j) acc[i][j] = 0.f;

    for (int h0 = hbase; h0 < hbase + klen; h0 += 32) {
        // ---- stage A (w1 chunk + b1): coalesced scalar loads (VOCAB odd ->
        //      row bases not float4-aligned), stride-1 LDS writes (free).
#pragma unroll
        for (int i = 0; i < 32; ++i) {
            int e   = t + 128 * i;        // 0..4095
            int row = e >> 7;             // hh 0..31
            int col = e & 127;
            int v   = v0 + col;
            float a = (full || v < VOCAB) ? w1[(size_t)(h0 + row) * VOCAB + v] : 0.f;
            lds_a[row * 132 + col] = a + b1[h0 + row];
        }
        // ---- stage B (w2^T chunk): float4 along h (w2 stride 512, aligned),
        //      4 scalar LDS writes at consecutive-l addresses (free).
#pragma unroll
        for (int i = 0; i < 4; ++i) {
            int e   = t + 128 * i;        // 0..511
            int hq  = e >> 6;             // 0..7
            int l   = e & 63;
            float4 bv = *(const float4*)&w2[l * HID + h0 + hq * 4];
            lds_b[(hq * 4 + 0) * 68 + l] = bv.x;
            lds_b[(hq * 4 + 1) * 68 + l] = bv.y;
            lds_b[(hq * 4 + 2) * 68 + l] = bv.z;
            lds_b[(hq * 4 + 3) * 68 + l] = bv.w;
        }
        __syncthreads();

#pragma unroll 4
        for (int hh = 0; hh < 32; ++hh) {
            float4 a0 = *(const float4*)&lds_a[hh * 132 + tx * 4];
            float4 a1 = *(const float4*)&lds_a[hh * 132 + 64 + tx * 4];
            float4 b0 = *(const float4*)&lds_b[hh * 68 + ty * 4];
            float4 b1v = *(const float4*)&lds_b[hh * 68 + 32 + ty * 4];
            float av[8] = {a0.x, a0.y, a0.z, a0.w, a1.x, a1.y, a1.z, a1.w};
            float bv[8] = {b0.x, b0.y, b0.z, b0.w, b1v.x, b1v.y, b1v.z, b1v.w};
#pragma unroll
            for (int i = 0; i < 8; ++i)
#pragma unroll
                for (int j = 0; j < 8; ++j)
                    acc[i][j] += av[i] * bv[j];
        }
        __syncthreads();
    }

    // ---- store: rows v = v0 + {tx*4+i, 64+tx*4+i}, cols {ty*4..+3, 32+ty*4..+3}
#pragma unroll
    for (int i = 0; i < 8; ++i) {
        int col = (i < 4) ? (tx * 4 + i) : (64 + tx * 4 + (i - 4));
        int v = v0 + col;
        if (full || v < VOCAB) {
            *(float4*)&Pout[(size_t)v * LABELS + ty * 4] =
                make_float4(acc[i][0], acc[i][1], acc[i][2], acc[i][3]);
            *(float4*)&Pout[(size_t)v * LABELS + 32 + ty * 4] =
                make_float4(acc[i][4], acc[i][5], acc[i][6], acc[i][7]);
        }
    }
}

// ---------------------------------------------------------------------------
// K2: out[tok][l] = sum_s P[s][idx[tok]][l] + b2[l]
// One float4 (4 labels) per thread; 16 threads per token. Partials L2/L3-hot.
// ---------------------------------------------------------------------------
__global__ __launch_bounds__(256) void gather_out(
    const int* __restrict__ idx,
    const float* __restrict__ P,
    const float* __restrict__ b2,
    float* __restrict__ out,
    int ntok, int ksplit)
{
    int g   = blockIdx.x * 256 + threadIdx.x;
    int tok = g >> 4;
    int j   = g & 15;
    if (tok >= ntok) return;
    int v = idx[tok];
    float4 s = ((const float4*)b2)[j];
    const float4* p = (const float4*)P + (size_t)v * 16 + j;
    for (int k = 0; k < ksplit; ++k) {
        float4 m = p[(size_t)k * VOCAB * 16];
        s.x += m.x; s.y += m.y; s.z += m.z; s.w += m.w;
    }
    ((float4*)out)[(size_t)tok * 16 + j] = s;
}

// ---------------------------------------------------------------------------
// Fallback (ws too small for any table): direct per-token dot.
// ---------------------------------------------------------------------------
__global__ __launch_bounds__(256) void direct_kernel(
    const int* __restrict__ idx,
    const float* __restrict__ w1,
    const float* __restrict__ b1,
    const float* __restrict__ w2,
    const float* __restrict__ b2,
    float* __restrict__ out,
    int ntok)
{
    int g   = blockIdx.x * 256 + threadIdx.x;
    int tok = g >> 6;
    int l   = g & 63;
    if (tok >= ntok) return;
    int v = idx[tok];
    float acc = b2[l];
    for (int h = 0; h < HID; ++h)
        acc += (w1[(size_t)h * VOCAB + v] + b1[h]) * w2[l * HID + h];
    out[(size_t)tok * 64 + l] = acc;
}

extern "C" void kernel_launch(void* const* d_in, const int* in_sizes, int n_in,
                              void* d_out, int out_size, void* d_ws, size_t ws_size,
                              hipStream_t stream) {
    const int*   idx = (const int*)d_in[0];
    const float* w1  = (const float*)d_in[1];
    const float* b1  = (const float*)d_in[2];
    const float* w2  = (const float*)d_in[3];
    const float* b2  = (const float*)d_in[4];
    float* out = (float*)d_out;
    const int ntok = in_sizes[0];   // 8*4096 = 32768

    const size_t table_bytes = (size_t)VOCAB * LABELS * sizeof(float);  // ~12.9 MB

    int ksplit = 0;
    if      (ws_size >= 4 * table_bytes) ksplit = 4;
    else if (ws_size >= 2 * table_bytes) ksplit = 2;
    else if (ws_size >= 1 * table_bytes) ksplit = 1;

    if (ksplit > 0) {
        float* P = (float*)d_ws;
        int klen = HID / ksplit;
        dim3 grid1((VOCAB + 127) / 128, ksplit);   // 393 x ksplit
        build_partial<<<grid1, 128, 0, stream>>>(w1, b1, w2, P, klen);
        int nblk2 = (ntok * 16 + 255) / 256;       // 2048
        gather_out<<<nblk2, 256, 0, stream>>>(idx, P, b2, out, ntok, ksplit);
    } else {
        int nblk = (ntok * 64 + 255) / 256;
        direct_kernel<<<nblk, 256, 0, stream>>>(idx, w1, b1, w2, b2, out, ntok);
    }
}

// Round 10
// 75.429 us; speedup vs baseline: 24.3569x; 1.6437x over previous
//
#include <hip/hip_runtime.h>
#include <hip/hip_bf16.h>

#define VOCAB 50257
#define HID 512
#define LABELS 64

// ---------------------------------------------------------------------------
// K0: C[l] = b2[l] + sum_h b1[h] * w2[l][h]   (v-independent bias term;
// lets the build kernel be a pure product — validated in R8 run)
// ---------------------------------------------------------------------------
__global__ void bias_combine(const float* __restrict__ b1,
                             const float* __restrict__ w2,
                             const float* __restrict__ b2,
                             float* __restrict__ C)
{
    int l = threadIdx.x;   // 64 threads
    float s = b2[l];
    for (int h = 0; h < HID; h += 4) {
        float4 wv = *(const float4*)&w2[l * HID + h];
        float4 bv = *(const float4*)&b1[h];
        s += wv.x * bv.x + wv.y * bv.y + wv.z * bv.z + wv.w * bv.w;
    }
    C[l] = s;
}

// ---------------------------------------------------------------------------
// K1 (fast path): P[s][v][l] = sum_{h in split s} w1[h,v]*w2[l,h]
// R7 geometry (256 thr, 64x64 tile, 4x4 acc, K chunks of 32, LDS stride 68,
// conflict-free staging) + T14 prefetch: chunk c+1's global loads issue into
// named register sets BEFORE chunk c's compute and are written to LDS after
// the barrier. Register loads are thread-private -> not drained at barriers.
// Named sets a0/a1, p0/p1 (no runtime-indexed reg arrays).
// ---------------------------------------------------------------------------
#define LOAD_CHUNK(areg, breg, h0)                                            \
    {                                                                         \
        if (full) {                                                           \
            _Pragma("unroll")                                                 \
            for (int i = 0; i < 8; ++i)                                       \
                areg[i] = w1[(size_t)((h0) + 4 * i + w) * VOCAB + vv];        \
        } else {                                                              \
            _Pragma("unroll")                                                 \
            for (int i = 0; i < 8; ++i)                                       \
                areg[i] = (vv < VOCAB)                                        \
                    ? w1[(size_t)((h0) + 4 * i + w) * VOCAB + vv] : 0.f;      \
        }                                                                     \
        _Pragma("unroll")                                                     \
        for (int i = 0; i < 2; ++i)                                           \
            breg[i] = *(const float4*)&w2[lane * HID + (h0) + (w + 4 * i) * 4]; \
    }

#define WRITE_CHUNK(areg, breg)                                               \
    {                                                                         \
        _Pragma("unroll")                                                     \
        for (int i = 0; i < 8; ++i)                                           \
            lds_a[(4 * i + w) * 68 + lane] = areg[i];                         \
        _Pragma("unroll")                                                     \
        for (int i = 0; i < 2; ++i) {                                         \
            int hr = (w + 4 * i) * 4;                                         \
            lds_b[(hr + 0) * 68 + lane] = breg[i].x;                          \
            lds_b[(hr + 1) * 68 + lane] = breg[i].y;                          \
            lds_b[(hr + 2) * 68 + lane] = breg[i].z;                          \
            lds_b[(hr + 3) * 68 + lane] = breg[i].w;                          \
        }                                                                     \
    }

#define COMPUTE_CHUNK()                                                       \
    {                                                                         \
        _Pragma("unroll 4")                                                   \
        for (int hh = 0; hh < 32; ++hh) {                                     \
            float4 a = *(const float4*)&lds_a[hh * 68 + tx * 4];              \
            float4 b = *(const float4*)&lds_b[hh * 68 + ty * 4];              \
            acc[0][0] += a.x * b.x; acc[0][1] += a.x * b.y;                   \
            acc[0][2] += a.x * b.z; acc[0][3] += a.x * b.w;                   \
            acc[1][0] += a.y * b.x; acc[1][1] += a.y * b.y;                   \
            acc[1][2] += a.y * b.z; acc[1][3] += a.y * b.w;                   \
            acc[2][0] += a.z * b.x; acc[2][1] += a.z * b.y;                   \
            acc[2][2] += a.z * b.z; acc[2][3] += a.z * b.w;                   \
            acc[3][0] += a.w * b.x; acc[3][1] += a.w * b.y;                   \
            acc[3][2] += a.w * b.z; acc[3][3] += a.w * b.w;                   \
        }                                                                     \
    }

__global__ __launch_bounds__(256) void build_partial(
    const float* __restrict__ w1,   // [HID][VOCAB]
    const float* __restrict__ w2,   // [LABELS][HID]
    float* __restrict__ P,          // [ksplit][VOCAB][LABELS]
    int klen)                       // multiple of 64 (nch even)
{
    __shared__ float lds_a[32 * 68];  // [hh][col]
    __shared__ float lds_b[32 * 68];  // [hh][label]

    const int t     = threadIdx.x;
    const int lane  = t & 63;
    const int w     = t >> 6;          // wave 0..3
    const int v0    = blockIdx.x * 64;
    const int hbase = blockIdx.y * klen;
    float* Pout = P + (size_t)blockIdx.y * VOCAB * LABELS;
    const int tx = t & 15;             // cols tx*4..+3
    const int ty = t >> 4;             // labels ty*4..+3
    const bool full = (v0 + 64 <= VOCAB);
    const int vv = v0 + lane;

    float acc[4][4] = {};

    float  a0[8], a1[8];
    float4 p0[2], p1[2];

    const int nch = klen >> 5;         // chunks of 32 rows

    LOAD_CHUNK(a0, p0, hbase);         // prologue: chunk 0 in flight

    for (int cp = 0; cp < nch; cp += 2) {
        // ---- even chunk: write set0, prefetch odd chunk, compute
        WRITE_CHUNK(a0, p0);           // waits on set0 loads (vmcnt)
        __syncthreads();
        if (cp + 1 < nch) LOAD_CHUNK(a1, p1, hbase + (cp + 1) * 32);
        COMPUTE_CHUNK();               // overlaps set1 flight time
        __syncthreads();

        if (cp + 1 < nch) {
            // ---- odd chunk: write set1, prefetch next even chunk, compute
            WRITE_CHUNK(a1, p1);
            __syncthreads();
            if (cp + 2 < nch) LOAD_CHUNK(a0, p0, hbase + (cp + 2) * 32);
            COMPUTE_CHUNK();
            __syncthreads();
        }
    }

#pragma unroll
    for (int i = 0; i < 4; ++i) {
        int v = v0 + tx * 4 + i;
        if (v < VOCAB) {
            *(float4*)&Pout[(size_t)v * LABELS + ty * 4] =
                make_float4(acc[i][0], acc[i][1], acc[i][2], acc[i][3]);
        }
    }
}

// ---------------------------------------------------------------------------
// K1 fallback (small ws): folded-b1 single-buffer version (R7, measured-good).
// ---------------------------------------------------------------------------
__global__ __launch_bounds__(256) void build_partial_folded(
    const float* __restrict__ w1,
    const float* __restrict__ b1,
    const float* __restrict__ w2,
    float* __restrict__ P,
    int klen)
{
    __shared__ float lds_a[32 * 68];
    __shared__ float lds_b[32 * 68];

    const int t     = threadIdx.x;
    const int v0    = blockIdx.x * 64;
    const int hbase = blockIdx.y * klen;
    float* Pout = P + (size_t)blockIdx.y * VOCAB * LABELS;
    const int tx = t & 15;
    const int ty = t >> 4;
    const bool full = (v0 + 64 <= VOCAB);

    float acc[4][4] = {};

    for (int h0 = hbase; h0 < hbase + klen; h0 += 32) {
#pragma unroll
        for (int i = 0; i < 8; ++i) {
            int e   = t + 256 * i;
            int row = e >> 6;
            int col = e & 63;
            int v   = v0 + col;
            float a = (full || v < VOCAB) ? w1[(size_t)(h0 + row) * VOCAB + v] : 0.f;
            lds_a[row * 68 + col] = a + b1[h0 + row];
        }
#pragma unroll
        for (int i = 0; i < 2; ++i) {
            int e   = t + 256 * i;
            int hh4 = e >> 6;
            int l   = e & 63;
            float4 bv = *(const float4*)&w2[l * HID + h0 + hh4 * 4];
            lds_b[(hh4 * 4 + 0) * 68 + l] = bv.x;
            lds_b[(hh4 * 4 + 1) * 68 + l] = bv.y;
            lds_b[(hh4 * 4 + 2) * 68 + l] = bv.z;
            lds_b[(hh4 * 4 + 3) * 68 + l] = bv.w;
        }
        __syncthreads();
#pragma unroll
        for (int hh = 0; hh < 32; ++hh) {
            float4 a = *(const float4*)&lds_a[hh * 68 + tx * 4];
            float4 b = *(const float4*)&lds_b[hh * 68 + ty * 4];
            acc[0][0] += a.x * b.x; acc[0][1] += a.x * b.y; acc[0][2] += a.x * b.z; acc[0][3] += a.x * b.w;
            acc[1][0] += a.y * b.x; acc[1][1] += a.y * b.y; acc[1][2] += a.y * b.z; acc[1][3] += a.y * b.w;
            acc[2][0] += a.z * b.x; acc[2][1] += a.z * b.y; acc[2][2] += a.z * b.z; acc[2][3] += a.z * b.w;
            acc[3][0] += a.w * b.x; acc[3][1] += a.w * b.y; acc[3][2] += a.w * b.z; acc[3][3] += a.w * b.w;
        }
        __syncthreads();
    }

#pragma unroll
    for (int i = 0; i < 4; ++i) {
        int v = v0 + tx * 4 + i;
        if (v < VOCAB) {
            *(float4*)&Pout[(size_t)v * LABELS + ty * 4] =
                make_float4(acc[i][0], acc[i][1], acc[i][2], acc[i][3]);
        }
    }
}

// ---------------------------------------------------------------------------
// K2: out[tok][l] = sum_s P[s][idx[tok]][l] + bias[l]
// ---------------------------------------------------------------------------
__global__ __launch_bounds__(256) void gather_out(
    const int* __restrict__ idx,
    const float* __restrict__ P,
    const float* __restrict__ bias,
    float* __restrict__ out,
    int ntok, int ksplit)
{
    int g   = blockIdx.x * 256 + threadIdx.x;
    int tok = g >> 4;
    int j   = g & 15;
    if (tok >= ntok) return;
    int v = idx[tok];
    float4 s = ((const float4*)bias)[j];
    const float4* p = (const float4*)P + (size_t)v * 16 + j;
    for (int k = 0; k < ksplit; ++k) {
        float4 m = p[(size_t)k * VOCAB * 16];
        s.x += m.x; s.y += m.y; s.z += m.z; s.w += m.w;
    }
    ((float4*)out)[(size_t)tok * 16 + j] = s;
}

// ---------------------------------------------------------------------------
// Fallback (ws too small for any table): direct per-token dot.
// ---------------------------------------------------------------------------
__global__ __launch_bounds__(256) void direct_kernel(
    const int* __restrict__ idx,
    const float* __restrict__ w1,
    const float* __restrict__ b1,
    const float* __restrict__ w2,
    const float* __restrict__ b2,
    float* __restrict__ out,
    int ntok)
{
    int g   = blockIdx.x * 256 + threadIdx.x;
    int tok = g >> 6;
    int l   = g & 63;
    if (tok >= ntok) return;
    int v = idx[tok];
    float acc = b2[l];
    for (int h = 0; h < HID; ++h)
        acc += (w1[(size_t)h * VOCAB + v] + b1[h]) * w2[l * HID + h];
    out[(size_t)tok * 64 + l] = acc;
}

extern "C" void kernel_launch(void* const* d_in, const int* in_sizes, int n_in,
                              void* d_out, int out_size, void* d_ws, size_t ws_size,
                              hipStream_t stream) {
    const int*   idx = (const int*)d_in[0];
    const float* w1  = (const float*)d_in[1];
    const float* b1  = (const float*)d_in[2];
    const float* w2  = (const float*)d_in[3];
    const float* b2  = (const float*)d_in[4];
    float* out = (float*)d_out;
    const int ntok = in_sizes[0];   // 8*4096 = 32768

    const size_t table_bytes = (size_t)VOCAB * LABELS * sizeof(float);  // ~12.9 MB
    const int nblk2 = (ntok * 16 + 255) / 256;                          // 2048

    if (ws_size >= 4 * table_bytes + 1024) {
        // fast path: prefetch build (pure product) + combined bias in ws tail
        float* P = (float*)d_ws;
        float* C = (float*)((char*)d_ws + 4 * table_bytes);
        bias_combine<<<1, 64, 0, stream>>>(b1, w2, b2, C);
        dim3 grid1((VOCAB + 63) / 64, 4);        // 786 x 4
        build_partial<<<grid1, 256, 0, stream>>>(w1, w2, P, HID / 4);
        gather_out<<<nblk2, 256, 0, stream>>>(idx, P, C, out, ntok, 4);
    } else {
        int ksplit = 0;
        if      (ws_size >= 4 * table_bytes) ksplit = 4;
        else if (ws_size >= 2 * table_bytes) ksplit = 2;
        else if (ws_size >= 1 * table_bytes) ksplit = 1;
        if (ksplit > 0) {
            float* P = (float*)d_ws;
            dim3 grid1((VOCAB + 63) / 64, ksplit);
            build_partial_folded<<<grid1, 256, 0, stream>>>(w1, b1, w2, P, HID / ksplit);
            gather_out<<<nblk2, 256, 0, stream>>>(idx, P, b2, out, ntok, ksplit);
        } else {
            int nblk = (ntok * 64 + 255) / 256;
            direct_kernel<<<nblk, 256, 0, stream>>>(idx, w1, b1, w2, b2, out, ntok);
        }
    }
}